// Round 5
// baseline (145.780 us; speedup 1.0000x reference)
//
#include <hip/hip_runtime.h>
#include <hip/hip_bf16.h>
#include <math.h>

// EntropyInvarianceAttention: out = softmax(c * Q^T K) V^T per (b,h),
// c = ln(k_length[b]) / (8*ln(20)); q,k,v are (B, 512, 2048) fp32, l contiguous.
//
// R11: attack the LDS pipe (R6->R10 showed 2x TLP gave only +6% => shared
// per-CU LDS unit is the limiter; traffic = 2MB/q_cov per block per tile).
//  - q_cov 32 -> 64 per wave (4 q-groups): halves K re-read redundancy.
//  - V moved OUT of LDS entirely: per tile each wave loads 4 x b128 V
//    fragments straight from workspace (L1/L2-resident, x2 redundancy only).
//    V deps are pure register dataflow -> compiler-managed, no race surface.
//    V double-buffered across tiles (named bufs, compile-time ping-pong).
//  - prep V relayout (Vt3): fragment-pack kb-pairs so one b128 per (tt,kh):
//    idx = ((kh*4+quad)*64 + d)*8 + tl*4 + i  <->  V[k=kh*32+tl*16+quad*4+i][d].
//  - LDS now: K 3-stage only (24KB) + 40KB epilogue area. Per CU per tile
//    LDS = 32KB K-reads + 16KB DMA vs R10's 160KB  (~4x cut).
//  - Sync = verified R6 skeleton, ALL waits vmcnt(0) (no counting: K(kt+1)
//    issued a full iteration earlier, drains free).
//  - 256 thr (4 waves: qh=wv&1 q-half, kh=wv>>1 k-half), 2 blocks/CU,
//    ~200 regs -> fits 2 waves/SIMD at <=256. Epilogue: single-round LDS
//    combine of k-halves (34.8KB <= 40KB), kh=0 normalizes + stores.
//  - ones-MFMA lsum kept (R9 showed VALU lsum regresses), no setprio.

typedef __attribute__((ext_vector_type(8))) short short8_t;
typedef __attribute__((ext_vector_type(4))) short short4_t;
typedef __attribute__((ext_vector_type(4))) float float4_t;

#define SEQ   2048
#define NBH   32
#define NKT   32

__device__ __forceinline__ unsigned f2bf2u(float a, float b) {
#if __has_builtin(__builtin_amdgcn_cvt_pk_bf16_f32)
  typedef __bf16 bf16x2_t __attribute__((ext_vector_type(2)));
  union { bf16x2_t v; unsigned u; } cv;
  cv.v = __builtin_amdgcn_cvt_pk_bf16_f32(a, b);
  return cv.u;
#else
  union { float f; unsigned u; } x, y;
  x.f = a; y.f = b;
  unsigned ra = x.u + 0x7fffu + ((x.u >> 16) & 1u);
  unsigned rb = y.u + 0x7fffu + ((y.u >> 16) & 1u);
  return (ra >> 16) | (rb & 0xffff0000u);
#endif
}

__device__ __forceinline__ short f2bf1(float a) {
  return (short)(f2bf2u(a, a) & 0xffffu);
}

__device__ __forceinline__ float fast_exp2(float x) {
#if __has_builtin(__builtin_amdgcn_exp2f)
  return __builtin_amdgcn_exp2f(x);
#else
  return exp2f(x);
#endif
}

__device__ __forceinline__ void gld16(const void* g, void* l) {
  __builtin_amdgcn_global_load_lds(
      (const __attribute__((address_space(1))) void*)g,
      (__attribute__((address_space(3))) void*)l, 16, 0, 0);
}

__device__ __forceinline__ float4_t mfma32(short8_t a, short8_t b, float4_t c) {
  return __builtin_amdgcn_mfma_f32_16x16x32_bf16(a, b, c, 0, 0, 0);
}

__device__ __forceinline__ float4_t mfma16(short4_t a, short4_t b, float4_t c) {
#if __has_builtin(__builtin_amdgcn_mfma_f32_16x16x16bf16_1k)
  return __builtin_amdgcn_mfma_f32_16x16x16bf16_1k(a, b, c, 0, 0, 0);
#else
  asm("v_mfma_f32_16x16x16_bf16 %0, %1, %2, %0" : "+v"(c) : "v"(a), "v"(b));
  return c;
#endif
}

// ---------------- fused pre-pass: K and V -> tile-blocked swizzled bf16 ----
// K -> Kt2[bh][kt][dc(8)][k(64)][8]  (unchanged, measured conflict-free).
// V -> Vt3[bh][kt]: idx = ((kh*4+quad)*64 + d)*8 + tl*4 + i
//                   = V[k = kh*32 + tl*16 + quad*4 + i][d]   (b128/frag-pair)
#define PST 68
__global__ __launch_bounds__(256, 8)
void eia_prep_kernel(const float* __restrict__ kg, const float* __restrict__ vg,
                     unsigned short* __restrict__ Kt2, unsigned short* __restrict__ Vt2) {
  __shared__ __align__(16) short T[64 * PST];
  const int id  = blockIdx.x;
  const int isV = id >> 10;
  const int sub = id & 1023;
  const int bh  = sub >> 5;
  const int kt  = sub & 31;
  const int t   = threadIdx.x;

  if (!isV) {
    const size_t ib = ((size_t)bh * 64) * SEQ + (size_t)(kt * 64) + (t & 63);
    const int dg = t >> 6;
#pragma unroll
    for (int dd = 0; dd < 16; dd += 4) {
      const int d = dg * 16 + dd;
      const float f0 = kg[ib + (size_t)(d + 0) * SEQ];
      const float f1 = kg[ib + (size_t)(d + 1) * SEQ];
      const float f2 = kg[ib + (size_t)(d + 2) * SEQ];
      const float f3 = kg[ib + (size_t)(d + 3) * SEQ];
      union { short4_t s; unsigned u[2]; } p;
      p.u[0] = f2bf2u(f0, f1);
      p.u[1] = f2bf2u(f2, f3);
      *(short4_t*)&T[(t & 63) * PST + d] = p.s;
    }
    __syncthreads();
    unsigned short* outt = Kt2 + (size_t)(bh * 32 + kt) * 4096;
#pragma unroll
    for (int rep = 0; rep < 2; ++rep) {
      const int id2 = rep * 256 + t;
      const int lr = id2 & 63, ch = id2 >> 6;
      union { short8_t v; short4_t h[2]; } o;
      o.h[0] = *(const short4_t*)&T[lr * PST + ch * 8];
      o.h[1] = *(const short4_t*)&T[lr * PST + ch * 8 + 4];
      *(short8_t*)&outt[ch * 512 + lr * 8] = o.v;
    }
  } else {
    // stage V[d][k-local] into T[d*PST + k]
#pragma unroll
    for (int rep = 0; rep < 4; ++rep) {
      const int id2 = rep * 256 + t;
      const int d = id2 >> 4, l4 = (id2 & 15) * 4;
      const float4_t f = *(const float4_t*)&vg[((size_t)bh * 64 + d) * SEQ + kt * 64 + l4];
      union { short4_t s; unsigned u[2]; } p;
      p.u[0] = f2bf2u(f[0], f[1]);
      p.u[1] = f2bf2u(f[2], f[3]);
      *(short4_t*)&T[d * PST + l4] = p.s;
    }
    __syncthreads();
    // Vt3 writeout: c in [0,512): kh = c>>8, quad = (c>>6)&3, d = c&63
    unsigned short* outt = Vt2 + (size_t)(bh * 32 + kt) * 4096;
#pragma unroll
    for (int rep = 0; rep < 2; ++rep) {
      const int c = rep * 256 + t;
      const int kh = c >> 8, quad = (c >> 6) & 3, d = c & 63;
      union { short8_t v; short4_t h[2]; } o;
      o.h[0] = *(const short4_t*)&T[d * PST + kh * 32 + quad * 4];        // tl=0
      o.h[1] = *(const short4_t*)&T[d * PST + kh * 32 + 16 + quad * 4];   // tl=1
      *(short8_t*)&outt[c * 8] = o.v;
    }
  }
}

// ---------------- main fused attention (R11: q64/wave, V-in-reg) ----------
// LDS (shorts): K stages [0,4096)|[4096,8192)|[8192,12288); SM total 20480
// shorts (40KB). Q staging overlays [0,8704); epilogue floats [0,34816B).
__global__ __launch_bounds__(256, 2)
void eia_attn_kernel(const float* __restrict__ qg,
                     const unsigned short* __restrict__ Kt2,
                     const unsigned short* __restrict__ Vt2,
                     const int* __restrict__ klen,
                     float* __restrict__ outg) {
  __shared__ __align__(16) short SM[20480];

  const int tid  = threadIdx.x;
  const int bh   = blockIdx.x & 31;   // XCD = bh%8; 512 blocks = 2/CU
  const int qt   = blockIdx.x >> 5;
  const int q0   = qt * 128;
  const int wv   = tid >> 6;          // wave 0..3
  const int qh   = wv & 1;            // q-half: q = qh*64 + g*16 + l16
  const int kh   = wv >> 1;           // k-half: k = kh*32 + tl*16 + quad*4 + i
  const int lane = tid & 63;
  const int quad = lane >> 4;
  const int l16  = lane & 15;

  const float c = (1.4426950408889634f / (8.0f * 2.9957322735539909f)) *
                  logf((float)klen[bh >> 3]);
  const size_t qb = (size_t)bh * 64 * SEQ;

  // ---- Q stage: fp32 global -> SM[q][d] bf16 (stride 68), c folded ----
#pragma unroll
  for (int rep = 0; rep < 8; ++rep) {
    const int id = rep * 256 + tid;       // 0..2047
    const int d  = id >> 5;               // 0..63
    const int q4 = (id & 31) * 4;
    const float4_t f = *(const float4_t*)&qg[qb + (size_t)d * SEQ + (size_t)(q0 + q4)];
    SM[(q4 + 0) * 68 + d] = f2bf1(c * f[0]);
    SM[(q4 + 1) * 68 + d] = f2bf1(c * f[1]);
    SM[(q4 + 2) * 68 + d] = f2bf1(c * f[2]);
    SM[(q4 + 3) * 68 + d] = f2bf1(c * f[3]);
  }
  __syncthreads();

  // Q B-fragments: B[kk=d=s*32+quad*8+j][n=q=l16], groups g=0..3
  short8_t qfrag[4][2];
#pragma unroll
  for (int g = 0; g < 4; ++g)
#pragma unroll
    for (int s = 0; s < 2; ++s) {
      const short* qp = &SM[(qh * 64 + g * 16 + l16) * 68 + s * 32 + quad * 8];
      const short4_t lo = *(const short4_t*)qp;
      const short4_t hi = *(const short4_t*)(qp + 4);
      qfrag[g][s] = short8_t{lo[0], lo[1], lo[2], lo[3], hi[0], hi[1], hi[2], hi[3]};
    }
  __syncthreads();  // Q reads done before DMA overwrites SM

  // ---- K DMA: tile = 8 x 1KB instrs over 4 waves = 2/wave ----
  const char* ksrc = (const char*)Kt2 + (size_t)bh * NKT * 8192 + (2 * wv) * 1024 + lane * 16;
  short* const kdst = &SM[(2 * wv) * 512];     // + stage*4096 (HW adds lane*16B)
  const short* const kfp = &SM[quad * 512 + l16 * 8];  // + koff + s*2048 + kb*128

  // ---- V global base (Vt3 layout), per-lane ----
  const char* const vgl = (const char*)Vt2 + (size_t)bh * NKT * 8192 +
                          kh * 4096 + quad * 1024 + l16 * 16;

  const float4_t z4 = {0.f, 0.f, 0.f, 0.f};
  float4_t oacc[4][4];
#pragma unroll
  for (int g = 0; g < 4; ++g)
#pragma unroll
    for (int tt = 0; tt < 4; ++tt) oacc[g][tt] = z4;
  float4_t lacc[4] = {z4, z4, z4, z4};
  const short one_bf = (short)0x3F80;
  const short4_t ones4 = (l16 == 0) ? short4_t{one_bf, one_bf, one_bf, one_bf}
                                    : short4_t{0, 0, 0, 0};

  // V register double-buffers (compile-time ping-pong; rule #20)
  union vfrag { short8_t v; short4_t h[2]; };
  vfrag vA[4], vB[4];

  // ---- prologue: DMA K tiles 0,1 -> stages 0,1; V(0) -> vA ----
  gld16(ksrc, kdst);               gld16(ksrc + 1024, kdst + 512);
  gld16(ksrc + 8192, kdst + 4096); gld16(ksrc + 8192 + 1024, kdst + 4096 + 512);
#pragma unroll
  for (int tt = 0; tt < 4; ++tt)
    vA[tt].v = *(const short8_t*)(vgl + tt * 256);

  int  sc = 0;              // stage (shorts offset/4096) of current tile
  int  sn = 2;              // stage of tile kt+2
  size_t gsrc = 2 * 8192;   // byte offset of tile kt+2

  // One body; VC = current V buf, VN = next V buf. All waits vmcnt(0):
  // K(kt) issued 2 iters ago, K(kt+1) 1 iter ago, V(kt) 1 iter ago -- all
  // landed or nearly; zero counting assumptions (R7/R8 lesson).
#define EIA_BODY(KT, VC, VN)                                                  \
  do {                                                                        \
    asm volatile("s_waitcnt vmcnt(0)" ::: "memory");                          \
    asm volatile("s_barrier" ::: "memory");                                   \
    if ((KT) < NKT - 2) {                                                     \
      const int so = sn * 4096;                                               \
      gld16(ksrc + gsrc, kdst + so);                                          \
      gld16(ksrc + gsrc + 1024, kdst + so + 512);                             \
      gsrc += 8192;                                                           \
      sn = (sn == 2) ? 0 : sn + 1;                                            \
    }                                                                         \
    if ((KT) < NKT - 1) {                                                     \
      const char* vp = vgl + (size_t)((KT) + 1) * 8192;                       \
      _Pragma("unroll")                                                       \
      for (int tt = 0; tt < 4; ++tt)                                          \
        VN[tt].v = *(const short8_t*)(vp + tt * 256);                         \
    }                                                                         \
    const int koff = sc * 4096;                                               \
    sc = (sc == 2) ? 0 : sc + 1;                                              \
    const short* const kb = kfp + koff;                                       \
    /* S^T = K^T * Q (this wave's k-half): 4 b128 reads, 16 mfma32 */         \
    float4_t sac[4][2];                                                       \
    _Pragma("unroll")                                                         \
    for (int tl = 0; tl < 2; ++tl) {                                          \
      const short8_t kv = *(const short8_t*)(kb + (kh * 2 + tl) * 128);       \
      _Pragma("unroll")                                                       \
      for (int g = 0; g < 4; ++g) sac[g][tl] = mfma32(kv, qfrag[g][0], z4);   \
    }                                                                         \
    _Pragma("unroll")                                                         \
    for (int tl = 0; tl < 2; ++tl) {                                          \
      const short8_t kv = *(const short8_t*)(kb + 2048 + (kh * 2 + tl) * 128);\
      _Pragma("unroll")                                                       \
      for (int g = 0; g < 4; ++g)                                             \
        sac[g][tl] = mfma32(kv, qfrag[g][1], sac[g][tl]);                     \
    }                                                                         \
    /* p = exp2(s); lsum via ones-MFMA (free on idle matrix pipe) */          \
    short4_t pbf[4][2];                                                       \
    _Pragma("unroll")                                                         \
    for (int g = 0; g < 4; ++g)                                               \
      _Pragma("unroll")                                                       \
      for (int tl = 0; tl < 2; ++tl) {                                        \
        const float e0 = fast_exp2(sac[g][tl][0]);                            \
        const float e1 = fast_exp2(sac[g][tl][1]);                            \
        const float e2 = fast_exp2(sac[g][tl][2]);                            \
        const float e3 = fast_exp2(sac[g][tl][3]);                            \
        union { short4_t s; unsigned u[2]; } p;                               \
        p.u[0] = f2bf2u(e0, e1);                                              \
        p.u[1] = f2bf2u(e2, e3);                                              \
        pbf[g][tl] = p.s;                                                     \
        lacc[g] = mfma16(ones4, pbf[g][tl], lacc[g]);                         \
      }                                                                       \
    /* O^T += V * P^T from registers: 32 mfma16 */                            \
    _Pragma("unroll")                                                         \
    for (int tt = 0; tt < 4; ++tt)                                            \
      _Pragma("unroll")                                                       \
      for (int tl = 0; tl < 2; ++tl) {                                        \
        const short4_t vv = VC[tt].h[tl];                                     \
        _Pragma("unroll")                                                     \
        for (int g = 0; g < 4; ++g)                                           \
          oacc[g][tt] = mfma16(vv, pbf[g][tl], oacc[g][tt]);                  \
      }                                                                       \
  } while (0)

  for (int kt = 0; kt < NKT; kt += 2) {
    EIA_BODY(kt,     vA, vB);
    EIA_BODY(kt + 1, vB, vA);
  }
#undef EIA_BODY

  // ---- epilogue: combine k-halves via LDS (single round), store ----
  __syncthreads();   // all waves done reading K stages
  float* const FA = (float*)SM;
  float* const fb = FA + (size_t)(qh * 64 + lane) * 68;   // 128 slots x 68 f
  if (kh == 1) {
#pragma unroll
    for (int g = 0; g < 4; ++g)
#pragma unroll
      for (int tt = 0; tt < 4; ++tt)
        *(float4_t*)(fb + (g * 4 + tt) * 4) = oacc[g][tt];
#pragma unroll
    for (int g = 0; g < 4; ++g) fb[64 + g] = lacc[g][0];
  }
  __syncthreads();
  if (kh == 0) {
#pragma unroll
    for (int g = 0; g < 4; ++g) {
#pragma unroll
      for (int tt = 0; tt < 4; ++tt) {
        const float4_t o2 = *(const float4_t*)(fb + (g * 4 + tt) * 4);
        oacc[g][tt][0] += o2[0];
        oacc[g][tt][1] += o2[1];
        oacc[g][tt][2] += o2[2];
        oacc[g][tt][3] += o2[3];
      }
      const float lsp = lacc[g][0] + fb[64 + g];
      const float ls  = __shfl(lsp, l16, 64);   // quad0 lanes hold row-0 sum
      const float inv = 1.0f / ls;
      const size_t ob = qb + (size_t)(q0 + qh * 64 + g * 16 + l16);
#pragma unroll
      for (int tt = 0; tt < 4; ++tt)
#pragma unroll
        for (int r = 0; r < 4; ++r)
          outg[ob + (size_t)(tt * 16 + quad * 4 + r) * SEQ] = oacc[g][tt][r] * inv;
    }
  }
}

// ---------------- fallback (ws too small): R2-style, known-good ----------------
#define DPAD  72
#define PPAD  68
__global__ __launch_bounds__(256, 5)
void eia_attn_fb(const float* __restrict__ qg, const float* __restrict__ kg,
                 const float* __restrict__ vg, const int* __restrict__ klen,
                 float* __restrict__ outg) {
  __shared__ __align__(16) short QPs[64 * DPAD];
  __shared__ __align__(16) short Ksf[64 * DPAD];
  __shared__ __align__(16) short Vsf[64 * DPAD];

  const int tid  = threadIdx.x;
  const int bh   = blockIdx.x & 31;
  const int qt   = blockIdx.x >> 5;
  const int q0   = qt * 64;
  const int w    = tid >> 6;
  const int lane = tid & 63;
  const int quad = lane >> 4;
  const int l16  = lane & 15;

  const size_t base = (size_t)bh * 64 * SEQ;
  const float c = (1.4426950408889634f / (8.0f * 2.9957322735539909f)) *
                  logf((float)klen[bh >> 3]);

#pragma unroll
  for (int it = 0; it < 2; ++it) {
    const int e = it * 4 + w;
    float f[8];
#pragma unroll
    for (int j = 0; j < 8; ++j)
      f[j] = c * qg[base + (size_t)(e * 8 + j) * SEQ + (size_t)(q0 + lane)];
    union { short8_t s8; unsigned u[4]; } t;
#pragma unroll
    for (int j = 0; j < 4; ++j) t.u[j] = f2bf2u(f[2 * j], f[2 * j + 1]);
    *(short8_t*)&QPs[lane * DPAD + e * 8] = t.s8;
  }
  __syncthreads();

  short8_t qfrag[2];
#pragma unroll
  for (int s = 0; s < 2; ++s)
    qfrag[s] = *(const short8_t*)&QPs[(w * 16 + l16) * DPAD + s * 32 + quad * 8];

  float4_t oacc[4];
#pragma unroll
  for (int t = 0; t < 4; ++t) { oacc[t][0] = 0.f; oacc[t][1] = 0.f; oacc[t][2] = 0.f; oacc[t][3] = 0.f; }
  float lsumv[4] = {0.f, 0.f, 0.f, 0.f};
  const int pbase = w * (16 * DPAD);

  for (int kt = 0; kt < NKT; ++kt) {
    const int k0 = kt * 64;
#pragma unroll
    for (int it = 0; it < 2; ++it) {
      float f[8];
#pragma unroll
      for (int j = 0; j < 8; ++j)
        f[j] = kg[base + (size_t)((it * 4 + w) * 8 + j) * SEQ + (size_t)(k0 + lane)];
      union { short8_t s8; unsigned u[4]; } t;
#pragma unroll
      for (int j = 0; j < 4; ++j) t.u[j] = f2bf2u(f[2 * j], f[2 * j + 1]);
      *(short8_t*)&Ksf[lane * DPAD + (it * 4 + w) * 8] = t.s8;
    }
#pragma unroll
    for (int it = 0; it < 4; ++it) {
      const int d = it * 16 + (w << 2) + (lane >> 4);
      const float4_t vv = *(const float4_t*)&vg[base + (size_t)d * SEQ + (size_t)(k0 + ((lane & 15) << 2))];
      union { short4_t s4; unsigned u[2]; } t;
      t.u[0] = f2bf2u(vv[0], vv[1]);
      t.u[1] = f2bf2u(vv[2], vv[3]);
      *(short4_t*)&Vsf[d * DPAD + ((lane & 15) << 2)] = t.s4;
    }
    __syncthreads();

    float4_t sacc[4];
#pragma unroll
    for (int t = 0; t < 4; ++t) { sacc[t][0] = 0.f; sacc[t][1] = 0.f; sacc[t][2] = 0.f; sacc[t][3] = 0.f; }
#pragma unroll
    for (int t = 0; t < 4; ++t)
#pragma unroll
      for (int s = 0; s < 2; ++s) {
        const short8_t bf = *(const short8_t*)&Ksf[(t * 16 + l16) * DPAD + s * 32 + quad * 8];
        sacc[t] = mfma32(qfrag[s], bf, sacc[t]);
      }

#pragma unroll
    for (int r = 0; r < 4; ++r) {
      const float p0 = fast_exp2(sacc[0][r]);
      const float p1 = fast_exp2(sacc[1][r]);
      const float p2 = fast_exp2(sacc[2][r]);
      const float p3 = fast_exp2(sacc[3][r]);
      lsumv[r] += (p0 + p1) + (p2 + p3);
      const int prow = pbase + (quad * 4 + r) * PPAD + l16;
      QPs[prow +  0] = f2bf1(p0);
      QPs[prow + 16] = f2bf1(p1);
      QPs[prow + 32] = f2bf1(p2);
      QPs[prow + 48] = f2bf1(p3);
    }

#pragma unroll
    for (int s = 0; s < 2; ++s) {
      const short* pr = &QPs[pbase + l16 * PPAD + s * 32 + quad * 8];
      const short4_t plo = *(const short4_t*)pr;
      const short4_t phi = *(const short4_t*)(pr + 4);
      const short8_t pf = {plo[0], plo[1], plo[2], plo[3], phi[0], phi[1], phi[2], phi[3]};
#pragma unroll
      for (int t = 0; t < 4; ++t) {
        const short8_t vf = *(const short8_t*)&Vsf[(t * 16 + l16) * DPAD + s * 32 + quad * 8];
        oacc[t] = mfma32(pf, vf, oacc[t]);
      }
    }
    __syncthreads();
  }

  float inv[4];
#pragma unroll
  for (int r = 0; r < 4; ++r) {
    float v = lsumv[r];
    v += __shfl_xor(v, 1);
    v += __shfl_xor(v, 2);
    v += __shfl_xor(v, 4);
    v += __shfl_xor(v, 8);
    inv[r] = 1.0f / v;
  }
#pragma unroll
  for (int t = 0; t < 4; ++t)
#pragma unroll
    for (int r = 0; r < 4; ++r)
      outg[base + (size_t)(t * 16 + l16) * SEQ +
           (size_t)(q0 + w * 16 + quad * 4 + r)] = oacc[t][r] * inv[r];
}

extern "C" void kernel_launch(void* const* d_in, const int* in_sizes, int n_in,
                              void* d_out, int out_size, void* d_ws, size_t ws_size,
                              hipStream_t stream) {
  const float* q  = (const float*)d_in[0];
  const float* k  = (const float*)d_in[1];
  const float* v  = (const float*)d_in[2];
  const int*   kl = (const int*)d_in[3];
  float* out = (float*)d_out;

  const size_t TEN  = (size_t)NBH * SEQ * 64;
  const size_t need = 2 * TEN * sizeof(unsigned short);  // 16.8 MB

  if (ws_size >= need) {
    unsigned short* Kt2 = (unsigned short*)d_ws;
    unsigned short* Vt2 = Kt2 + TEN;
    eia_prep_kernel<<<2048, 256, 0, stream>>>(k, v, Kt2, Vt2);
    eia_attn_kernel<<<512, 256, 0, stream>>>(q, Kt2, Vt2, kl, out);
  } else {
    eia_attn_fb<<<1024, 256, 0, stream>>>(q, k, v, kl, out);
  }
}

// Round 6
// 139.788 us; speedup vs baseline: 1.0429x; 1.0429x over previous
//
#include <hip/hip_runtime.h>
#include <hip/hip_bf16.h>
#include <math.h>

// EntropyInvarianceAttention: out = softmax(c * Q^T K) V^T per (b,h),
// c = ln(k_length[b]) / (8*ln(20)); q,k,v are (B, 512, 2048) fp32, l contiguous.
//
// R12: all-full-rate MFMA path (32x32x16) replacing the half-rate 16x16x16 PV.
//  - R10/R11 post-mortem: HBM 6%, LDS-pipe not binding (R11's 4x traffic cut
//    didn't help), TLP weak lever (+6%). Remaining: PV ran at K=16 half rate;
//    48 MFMA/wave/tile -> 16 full-rate 32x32x16 (QK 8 + PV 8).
//  - P repack C(QK)->B(PV) via cvt_pk_bf16 + v_permlane32_swap (T12):
//    per 32x32 S-tile: 8 cvt + 4 swaps. Mapping (verified by trace):
//    C row = (r&3)+8*(r>>2)+4*hi, col q = lane&31 (HW-verified m74/m101).
//    B[k=hi*8+j][q]: swap(cvt(e0,e1),cvt(e4,e5)) -> regs t0,t2;
//                    swap(cvt(e2,e3),cvt(e6,e7)) -> regs t1,t3 (per 16-k step).
//  - lsum: lane's C-col is a single q -> 15 VALU adds/tile, one final
//    shfl_xor(32); normalize needs NO broadcast (lane's 32 outputs share q).
//  - K LDS image unchanged (Kt2); V prep relayout Vt3[kc(8)][d(64)][8]
//    (= V[k=kc*8+j][d]) so each PV A-frag is one ds_read_b128.
//  - Sync skeleton BYTE-IDENTICAL to proven R6/R9/R10 loop: 3-stage LDS
//    {K 8KB | V 8KB}, 4 gld16/wave/tile, prologue vmcnt(0) drain, steady
//    vmcnt(4), raw barrier, DMA(kt+2). 256 thr, 4 waves = one 32-q tile each.

typedef __attribute__((ext_vector_type(8))) short short8_t;
typedef __attribute__((ext_vector_type(4))) short short4_t;
typedef __attribute__((ext_vector_type(4))) float float4_t;
typedef __attribute__((ext_vector_type(16))) float float16_t;

#define SEQ   2048
#define NBH   32
#define NKT   32

__device__ __forceinline__ unsigned f2bf2u(float a, float b) {
#if __has_builtin(__builtin_amdgcn_cvt_pk_bf16_f32)
  typedef __bf16 bf16x2_t __attribute__((ext_vector_type(2)));
  union { bf16x2_t v; unsigned u; } cv;
  cv.v = __builtin_amdgcn_cvt_pk_bf16_f32(a, b);
  return cv.u;
#else
  union { float f; unsigned u; } x, y;
  x.f = a; y.f = b;
  unsigned ra = x.u + 0x7fffu + ((x.u >> 16) & 1u);
  unsigned rb = y.u + 0x7fffu + ((y.u >> 16) & 1u);
  return (ra >> 16) | (rb & 0xffff0000u);
#endif
}

__device__ __forceinline__ short f2bf1(float a) {
  return (short)(f2bf2u(a, a) & 0xffffu);
}

__device__ __forceinline__ float fast_exp2(float x) {
#if __has_builtin(__builtin_amdgcn_exp2f)
  return __builtin_amdgcn_exp2f(x);
#else
  return exp2f(x);
#endif
}

__device__ __forceinline__ void gld16(const void* g, void* l) {
  __builtin_amdgcn_global_load_lds(
      (const __attribute__((address_space(1))) void*)g,
      (__attribute__((address_space(3))) void*)l, 16, 0, 0);
}

__device__ __forceinline__ float4_t mfma32(short8_t a, short8_t b, float4_t c) {
  return __builtin_amdgcn_mfma_f32_16x16x32_bf16(a, b, c, 0, 0, 0);
}

__device__ __forceinline__ float16_t mfma3232(short8_t a, short8_t b, float16_t c) {
  return __builtin_amdgcn_mfma_f32_32x32x16_bf16(a, b, c, 0, 0, 0);
}

// lane<32/lane>=32 half exchange: a' = [a_lo|b_lo], b' = [a_hi|b_hi]
__device__ __forceinline__ void plswap(unsigned& a, unsigned& b, int hi) {
#if __has_builtin(__builtin_amdgcn_permlane32_swap)
  typedef __attribute__((ext_vector_type(2))) unsigned uint2_t;
  uint2_t r = __builtin_amdgcn_permlane32_swap(a, b, false, false);
  a = r[0]; b = r[1];
#else
  const unsigned sa = (unsigned)__shfl_xor((int)a, 32);
  const unsigned sb = (unsigned)__shfl_xor((int)b, 32);
  const unsigned an = hi ? sb : a;
  const unsigned bn = hi ? b : sa;
  a = an; b = bn;
#endif
}

// ---------------- fused pre-pass: K and V -> tile-blocked swizzled bf16 ----
// K -> Kt2[bh][kt][dc(8)][k(64)][8]  (unchanged, measured conflict-free).
// V -> Vt3[bh][kt][kc(8)][d(64)][8]: elem (kc*64+d)*8+j = V[k=kc*8+j][d].
#define PST 68
__global__ __launch_bounds__(256, 8)
void eia_prep_kernel(const float* __restrict__ kg, const float* __restrict__ vg,
                     unsigned short* __restrict__ Kt2, unsigned short* __restrict__ Vt2) {
  __shared__ __align__(16) short T[64 * PST];
  const int id  = blockIdx.x;
  const int isV = id >> 10;
  const int sub = id & 1023;
  const int bh  = sub >> 5;
  const int kt  = sub & 31;
  const int t   = threadIdx.x;

  if (!isV) {
    const size_t ib = ((size_t)bh * 64) * SEQ + (size_t)(kt * 64) + (t & 63);
    const int dg = t >> 6;
#pragma unroll
    for (int dd = 0; dd < 16; dd += 4) {
      const int d = dg * 16 + dd;
      const float f0 = kg[ib + (size_t)(d + 0) * SEQ];
      const float f1 = kg[ib + (size_t)(d + 1) * SEQ];
      const float f2 = kg[ib + (size_t)(d + 2) * SEQ];
      const float f3 = kg[ib + (size_t)(d + 3) * SEQ];
      union { short4_t s; unsigned u[2]; } p;
      p.u[0] = f2bf2u(f0, f1);
      p.u[1] = f2bf2u(f2, f3);
      *(short4_t*)&T[(t & 63) * PST + d] = p.s;
    }
    __syncthreads();
    unsigned short* outt = Kt2 + (size_t)(bh * 32 + kt) * 4096;
#pragma unroll
    for (int rep = 0; rep < 2; ++rep) {
      const int id2 = rep * 256 + t;
      const int lr = id2 & 63, ch = id2 >> 6;
      union { short8_t v; short4_t h[2]; } o;
      o.h[0] = *(const short4_t*)&T[lr * PST + ch * 8];
      o.h[1] = *(const short4_t*)&T[lr * PST + ch * 8 + 4];
      *(short8_t*)&outt[ch * 512 + lr * 8] = o.v;
    }
  } else {
    // stage V[d][k-local] into T[d*PST + k]
#pragma unroll
    for (int rep = 0; rep < 4; ++rep) {
      const int id2 = rep * 256 + t;
      const int d = id2 >> 4, l4 = (id2 & 15) * 4;
      const float4_t f = *(const float4_t*)&vg[((size_t)bh * 64 + d) * SEQ + kt * 64 + l4];
      union { short4_t s; unsigned u[2]; } p;
      p.u[0] = f2bf2u(f[0], f[1]);
      p.u[1] = f2bf2u(f[2], f[3]);
      *(short4_t*)&T[d * PST + l4] = p.s;
    }
    __syncthreads();
    // Vt3 writeout: c in [0,512): kc = c>>6 (8 k-chunks), d = c&63
    unsigned short* outt = Vt2 + (size_t)(bh * 32 + kt) * 4096;
#pragma unroll
    for (int rep = 0; rep < 2; ++rep) {
      const int c = rep * 256 + t;
      const int kc = c >> 6, d = c & 63;
      union { short8_t v; short4_t h[2]; } o;
      o.h[0] = *(const short4_t*)&T[d * PST + kc * 8];
      o.h[1] = *(const short4_t*)&T[d * PST + kc * 8 + 4];
      *(short8_t*)&outt[c * 8] = o.v;
    }
  }
}

// ---------------- main fused attention (R12: 32x32 MFMA path) ----------
// LDS (shorts): K stages [0,4096)|[4096,8192)|[8192,12288)
//               V stages [12288,16384)|[16384,20480)|[20480,24576)
// Q staging overlays [0, 8704) before the first DMA.
__global__ __launch_bounds__(256, 2)
void eia_attn_kernel(const float* __restrict__ qg,
                     const unsigned short* __restrict__ Kt2,
                     const unsigned short* __restrict__ Vt2,
                     const int* __restrict__ klen,
                     float* __restrict__ outg) {
  __shared__ __align__(16) short SM[24576];

  const int tid   = threadIdx.x;
  const int bh    = blockIdx.x & 31;   // XCD = bh%8; 512 blocks = 2/CU
  const int qt    = blockIdx.x >> 5;
  const int q0    = qt * 128;
  const int qw    = tid >> 6;          // wave 0..3: q-tile qw*32
  const int lane  = tid & 63;
  const int l31   = lane & 31;
  const int hi    = lane >> 5;

  const float c = (1.4426950408889634f / (8.0f * 2.9957322735539909f)) *
                  logf((float)klen[bh >> 3]);
  const size_t qb = (size_t)bh * 64 * SEQ;

  // ---- Q stage: fp32 global -> SM[q][d] bf16 (stride 68), c folded ----
#pragma unroll
  for (int rep = 0; rep < 8; ++rep) {
    const int id = rep * 256 + tid;       // 0..2047
    const int d  = id >> 5;               // 0..63
    const int q4 = (id & 31) * 4;
    const float4_t f = *(const float4_t*)&qg[qb + (size_t)d * SEQ + (size_t)(q0 + q4)];
    SM[(q4 + 0) * 68 + d] = f2bf1(c * f[0]);
    SM[(q4 + 1) * 68 + d] = f2bf1(c * f[1]);
    SM[(q4 + 2) * 68 + d] = f2bf1(c * f[2]);
    SM[(q4 + 3) * 68 + d] = f2bf1(c * f[3]);
  }
  __syncthreads();

  // Q B-fragments (32x32x16 B-layout): B[d=s*16+hi*8+j][q=l31], s=0..3
  short8_t qfrag[4];
#pragma unroll
  for (int s = 0; s < 4; ++s) {
    const short* qp = &SM[(qw * 32 + l31) * 68 + s * 16 + hi * 8];
    const short4_t lo = *(const short4_t*)qp;
    const short4_t hh = *(const short4_t*)(qp + 4);
    qfrag[s] = short8_t{lo[0], lo[1], lo[2], lo[3], hh[0], hh[1], hh[2], hh[3]};
  }
  __syncthreads();  // Q reads done before DMA overwrites SM

  // ---- DMA setup: tile = 8 x 1KB instrs; wave qw covers instrs 2qw, 2qw+1 ----
  const char* ksrc = (const char*)Kt2 + (size_t)bh * NKT * 8192 + (2 * qw) * 1024 + lane * 16;
  const char* vsrc = (const char*)Vt2 + (size_t)bh * NKT * 8192 + (2 * qw) * 1024 + lane * 16;
  short* const kdst = &SM[(2 * qw) * 512];            // + stage*4096 (HW adds lane*16B)
  short* const vdst = &SM[12288 + (2 * qw) * 512];

  // per-lane invariant fragment offset (shorts): hi*512 + l31*8
  const int lofs = hi * 512 + l31 * 8;

  const float16_t z16 = {0.f,0.f,0.f,0.f,0.f,0.f,0.f,0.f,
                         0.f,0.f,0.f,0.f,0.f,0.f,0.f,0.f};
  float16_t oacc0 = z16, oacc1 = z16;   // dt = 0,1
  float ls = 0.f;

  // ---- prologue: DMA tiles 0,1 -> stages 0,1 (4 loads/wave/tile) ----
  gld16(ksrc, kdst);               gld16(ksrc + 1024, kdst + 512);
  gld16(vsrc, vdst);               gld16(vsrc + 1024, vdst + 512);
  gld16(ksrc + 8192, kdst + 4096); gld16(ksrc + 8192 + 1024, kdst + 4096 + 512);
  gld16(vsrc + 8192, vdst + 4096); gld16(vsrc + 8192 + 1024, vdst + 4096 + 512);
  // One-time full drain: no issue-order assumption on prologue loads (R9-proven).
  asm volatile("s_waitcnt vmcnt(0)" ::: "memory");

  int  sc = 0;              // stage (shorts offset/4096) of current tile
  int  sn = 2;              // stage of tile kt+2
  size_t gsrc = 2 * 8192;   // byte offset of tile kt+2

  for (int kt = 0; kt < NKT; ++kt) {
    // wait: current tile's 4 loads done; NEXT tile's 4 stay in flight.
    if (kt < NKT - 1) asm volatile("s_waitcnt vmcnt(4)" ::: "memory");
    else              asm volatile("s_waitcnt vmcnt(0)" ::: "memory");
    asm volatile("s_barrier" ::: "memory");

    // issue DMA for tile kt+2 into stage sn (2 compute sections to land)
    if (kt < NKT - 2) {
      const int so = sn * 4096;
      gld16(ksrc + gsrc, kdst + so); gld16(ksrc + gsrc + 1024, kdst + so + 512);
      gld16(vsrc + gsrc, vdst + so); gld16(vsrc + gsrc + 1024, vdst + so + 512);
      gsrc += 8192;
      sn = (sn == 2) ? 0 : sn + 1;
    }
    const int koff = sc * 4096;
    sc = (sc == 2) ? 0 : sc + 1;
    const short* const kb_ = &SM[koff + lofs];           // + kb*256 + s*1024
    const short* const vb_ = &SM[12288 + koff + lofs];   // + dt*256 + ks*1024

    // ---- S^T = K^T * Q : 2 kb-tiles x 4 chained mfma_32x32x16 ----
    float16_t s0 = z16, s1 = z16;
#pragma unroll
    for (int s = 0; s < 4; ++s)
      s0 = mfma3232(*(const short8_t*)(kb_ + s * 1024), qfrag[s], s0);
#pragma unroll
    for (int s = 0; s < 4; ++s)
      s1 = mfma3232(*(const short8_t*)(kb_ + 256 + s * 1024), qfrag[s], s1);

    // ---- exp + lsum + P repack (C->B via cvt_pk + permlane32_swap) ----
    union pfu { short8_t s8; unsigned u[4]; };
    pfu pf[4];
#pragma unroll
    for (int kb = 0; kb < 2; ++kb) {
      float e[16];
#pragma unroll
      for (int r = 0; r < 16; ++r)
        e[r] = fast_exp2(kb == 0 ? s0[r] : s1[r]);
      ls += (((e[0] + e[1]) + (e[2] + e[3])) + ((e[4] + e[5]) + (e[6] + e[7]))) +
            (((e[8] + e[9]) + (e[10] + e[11])) + ((e[12] + e[13]) + (e[14] + e[15])));
#pragma unroll
      for (int ksl = 0; ksl < 2; ++ksl) {
        const int b = ksl * 8;
        unsigned a02 = f2bf2u(e[b + 0], e[b + 1]);
        unsigned b02 = f2bf2u(e[b + 4], e[b + 5]);
        unsigned a13 = f2bf2u(e[b + 2], e[b + 3]);
        unsigned b13 = f2bf2u(e[b + 6], e[b + 7]);
        plswap(a02, b02, hi);   // a02 -> reg t0, b02 -> reg t2
        plswap(a13, b13, hi);   // a13 -> reg t1, b13 -> reg t3
        pf[kb * 2 + ksl].u[0] = a02;
        pf[kb * 2 + ksl].u[1] = a13;
        pf[kb * 2 + ksl].u[2] = b02;
        pf[kb * 2 + ksl].u[3] = b13;
      }
    }

    // ---- O^T += V * P^T : 2 dt-tiles x 4 chained mfma_32x32x16 ----
#pragma unroll
    for (int ks = 0; ks < 4; ++ks)
      oacc0 = mfma3232(*(const short8_t*)(vb_ + ks * 1024), pf[ks].s8, oacc0);
#pragma unroll
    for (int ks = 0; ks < 4; ++ks)
      oacc1 = mfma3232(*(const short8_t*)(vb_ + 256 + ks * 1024), pf[ks].s8, oacc1);
  }

  // ---- epilogue: lsum cross-half add, normalize (lane's q = l31), store ----
  const float lst = ls + __shfl_xor(ls, 32);
  const float inv = 1.0f / lst;
  const size_t ob = qb + (size_t)(q0 + qw * 32 + l31);
#pragma unroll
  for (int r = 0; r < 16; ++r) {
    const int drow = (r & 3) + 8 * (r >> 2) + 4 * hi;
    outg[ob + (size_t)(drow) * SEQ]      = oacc0[r] * inv;
    outg[ob + (size_t)(drow + 32) * SEQ] = oacc1[r] * inv;
  }
}

// ---------------- fallback (ws too small): R2-style, known-good ----------------
#define DPAD  72
#define PPAD  68
__global__ __launch_bounds__(256, 5)
void eia_attn_fb(const float* __restrict__ qg, const float* __restrict__ kg,
                 const float* __restrict__ vg, const int* __restrict__ klen,
                 float* __restrict__ outg) {
  __shared__ __align__(16) short QPs[64 * DPAD];
  __shared__ __align__(16) short Ksf[64 * DPAD];
  __shared__ __align__(16) short Vsf[64 * DPAD];

  const int tid  = threadIdx.x;
  const int bh   = blockIdx.x & 31;
  const int qt   = blockIdx.x >> 5;
  const int q0   = qt * 64;
  const int w    = tid >> 6;
  const int lane = tid & 63;
  const int quad = lane >> 4;
  const int l16  = lane & 15;

  const size_t base = (size_t)bh * 64 * SEQ;
  const float c = (1.4426950408889634f / (8.0f * 2.9957322735539909f)) *
                  logf((float)klen[bh >> 3]);

#pragma unroll
  for (int it = 0; it < 2; ++it) {
    const int e = it * 4 + w;
    float f[8];
#pragma unroll
    for (int j = 0; j < 8; ++j)
      f[j] = c * qg[base + (size_t)(e * 8 + j) * SEQ + (size_t)(q0 + lane)];
    union { short8_t s8; unsigned u[4]; } t;
#pragma unroll
    for (int j = 0; j < 4; ++j) t.u[j] = f2bf2u(f[2 * j], f[2 * j + 1]);
    *(short8_t*)&QPs[lane * DPAD + e * 8] = t.s8;
  }
  __syncthreads();

  short8_t qfrag[2];
#pragma unroll
  for (int s = 0; s < 2; ++s)
    qfrag[s] = *(const short8_t*)&QPs[(w * 16 + l16) * DPAD + s * 32 + quad * 8];

  float4_t oacc[4];
#pragma unroll
  for (int t = 0; t < 4; ++t) { oacc[t][0] = 0.f; oacc[t][1] = 0.f; oacc[t][2] = 0.f; oacc[t][3] = 0.f; }
  float lsumv[4] = {0.f, 0.f, 0.f, 0.f};
  const int pbase = w * (16 * DPAD);

  for (int kt = 0; kt < NKT; ++kt) {
    const int k0 = kt * 64;
#pragma unroll
    for (int it = 0; it < 2; ++it) {
      float f[8];
#pragma unroll
      for (int j = 0; j < 8; ++j)
        f[j] = kg[base + (size_t)((it * 4 + w) * 8 + j) * SEQ + (size_t)(k0 + lane)];
      union { short8_t s8; unsigned u[4]; } t;
#pragma unroll
      for (int j = 0; j < 4; ++j) t.u[j] = f2bf2u(f[2 * j], f[2 * j + 1]);
      *(short8_t*)&Ksf[lane * DPAD + (it * 4 + w) * 8] = t.s8;
    }
#pragma unroll
    for (int it = 0; it < 4; ++it) {
      const int d = it * 16 + (w << 2) + (lane >> 4);
      const float4_t vv = *(const float4_t*)&vg[base + (size_t)d * SEQ + (size_t)(k0 + ((lane & 15) << 2))];
      union { short4_t s4; unsigned u[2]; } t;
      t.u[0] = f2bf2u(vv[0], vv[1]);
      t.u[1] = f2bf2u(vv[2], vv[3]);
      *(short4_t*)&Vsf[d * DPAD + ((lane & 15) << 2)] = t.s4;
    }
    __syncthreads();

    float4_t sacc[4];
#pragma unroll
    for (int t = 0; t < 4; ++t) { sacc[t][0] = 0.f; sacc[t][1] = 0.f; sacc[t][2] = 0.f; sacc[t][3] = 0.f; }
#pragma unroll
    for (int t = 0; t < 4; ++t)
#pragma unroll
      for (int s = 0; s < 2; ++s) {
        const short8_t bf = *(const short8_t*)&Ksf[(t * 16 + l16) * DPAD + s * 32 + quad * 8];
        sacc[t] = mfma32(qfrag[s], bf, sacc[t]);
      }

#pragma unroll
    for (int r = 0; r < 4; ++r) {
      const float p0 = fast_exp2(sacc[0][r]);
      const float p1 = fast_exp2(sacc[1][r]);
      const float p2 = fast_exp2(sacc[2][r]);
      const float p3 = fast_exp2(sacc[3][r]);
      lsumv[r] += (p0 + p1) + (p2 + p3);
      const int prow = pbase + (quad * 4 + r) * PPAD + l16;
      QPs[prow +  0] = f2bf1(p0);
      QPs[prow + 16] = f2bf1(p1);
      QPs[prow + 32] = f2bf1(p2);
      QPs[prow + 48] = f2bf1(p3);
    }

#pragma unroll
    for (int s = 0; s < 2; ++s) {
      const short* pr = &QPs[pbase + l16 * PPAD + s * 32 + quad * 8];
      const short4_t plo = *(const short4_t*)pr;
      const short4_t phi = *(const short4_t*)(pr + 4);
      const short8_t pfv = {plo[0], plo[1], plo[2], plo[3], phi[0], phi[1], phi[2], phi[3]};
#pragma unroll
      for (int t = 0; t < 4; ++t) {
        const short8_t vf = *(const short8_t*)&Vsf[(t * 16 + l16) * DPAD + s * 32 + quad * 8];
        oacc[t] = mfma32(pfv, vf, oacc[t]);
      }
    }
    __syncthreads();
  }

  float inv[4];
#pragma unroll
  for (int r = 0; r < 4; ++r) {
    float v = lsumv[r];
    v += __shfl_xor(v, 1);
    v += __shfl_xor(v, 2);
    v += __shfl_xor(v, 4);
    v += __shfl_xor(v, 8);
    inv[r] = 1.0f / v;
  }
#pragma unroll
  for (int t = 0; t < 4; ++t)
#pragma unroll
    for (int r = 0; r < 4; ++r)
      outg[base + (size_t)(t * 16 + l16) * SEQ +
           (size_t)(q0 + w * 16 + quad * 4 + r)] = oacc[t][r] * inv[r];
}

extern "C" void kernel_launch(void* const* d_in, const int* in_sizes, int n_in,
                              void* d_out, int out_size, void* d_ws, size_t ws_size,
                              hipStream_t stream) {
  const float* q  = (const float*)d_in[0];
  const float* k  = (const float*)d_in[1];
  const float* v  = (const float*)d_in[2];
  const int*   kl = (const int*)d_in[3];
  float* out = (float*)d_out;

  const size_t TEN  = (size_t)NBH * SEQ * 64;
  const size_t need = 2 * TEN * sizeof(unsigned short);  // 16.8 MB

  if (ws_size >= need) {
    unsigned short* Kt2 = (unsigned short*)d_ws;
    unsigned short* Vt2 = Kt2 + TEN;
    eia_prep_kernel<<<2048, 256, 0, stream>>>(k, v, Kt2, Vt2);
    eia_attn_kernel<<<512, 256, 0, stream>>>(q, Kt2, Vt2, kl, out);
  } else {
    eia_attn_fb<<<1024, 256, 0, stream>>>(q, k, v, kl, out);
  }
}

// Round 7
// 139.636 us; speedup vs baseline: 1.0440x; 1.0011x over previous
//
#include <hip/hip_runtime.h>
#include <hip/hip_bf16.h>
#include <math.h>

// EntropyInvarianceAttention: out = softmax(c * Q^T K) V^T per (b,h),
// c = ln(k_length[b]) / (8*ln(20)); q,k,v are (B, 512, 2048) fp32, l contiguous.
//
// R13 = R12 attn (verified 58.4us, UNTOUCHED) + prep rewrite.
//  Cross-round accounting: total - attn ~= 80us in ALL six rounds -> the
//  prep kernel (+fixed overhead) costs more than attn itself. Prep BW floor
//  ~10us; it was 4-5x off: K-branch used 16 scalar 4B loads/thread and the
//  2048-block two-pass launch. R13 prep:
//   - 1024 blocks: one (bh,kt) block does K phase then V phase, reusing the
//     same LDS tile (extra __syncthreads between phases).
//   - K staging: float4 loads along k (4/thread), bf16-convert, scatter to
//     T[k][d] (16 scalar LDS writes — LDS is cheap, HBM instrs 4x fewer).
//   - V staging + BOTH writeouts byte-identical to the proven R12 layouts:
//     Kt2[bh][kt][ch(8)][lr(64)][8] (= K^T tile), Vt3[bh][kt][kc(8)][d(64)][8].
//  Attn kernel: R12 all-full-rate 32x32x16 path, 3-stage LDS, proven sync
//  skeleton (prologue vmcnt(0), steady vmcnt(4), raw barrier, DMA(kt+2)).

typedef __attribute__((ext_vector_type(8))) short short8_t;
typedef __attribute__((ext_vector_type(4))) short short4_t;
typedef __attribute__((ext_vector_type(4))) float float4_t;
typedef __attribute__((ext_vector_type(16))) float float16_t;

#define SEQ   2048
#define NBH   32
#define NKT   32

__device__ __forceinline__ unsigned f2bf2u(float a, float b) {
#if __has_builtin(__builtin_amdgcn_cvt_pk_bf16_f32)
  typedef __bf16 bf16x2_t __attribute__((ext_vector_type(2)));
  union { bf16x2_t v; unsigned u; } cv;
  cv.v = __builtin_amdgcn_cvt_pk_bf16_f32(a, b);
  return cv.u;
#else
  union { float f; unsigned u; } x, y;
  x.f = a; y.f = b;
  unsigned ra = x.u + 0x7fffu + ((x.u >> 16) & 1u);
  unsigned rb = y.u + 0x7fffu + ((y.u >> 16) & 1u);
  return (ra >> 16) | (rb & 0xffff0000u);
#endif
}

__device__ __forceinline__ short f2bf1(float a) {
  return (short)(f2bf2u(a, a) & 0xffffu);
}

__device__ __forceinline__ float fast_exp2(float x) {
#if __has_builtin(__builtin_amdgcn_exp2f)
  return __builtin_amdgcn_exp2f(x);
#else
  return exp2f(x);
#endif
}

__device__ __forceinline__ void gld16(const void* g, void* l) {
  __builtin_amdgcn_global_load_lds(
      (const __attribute__((address_space(1))) void*)g,
      (__attribute__((address_space(3))) void*)l, 16, 0, 0);
}

__device__ __forceinline__ float4_t mfma32(short8_t a, short8_t b, float4_t c) {
  return __builtin_amdgcn_mfma_f32_16x16x32_bf16(a, b, c, 0, 0, 0);
}

__device__ __forceinline__ float16_t mfma3232(short8_t a, short8_t b, float16_t c) {
  return __builtin_amdgcn_mfma_f32_32x32x16_bf16(a, b, c, 0, 0, 0);
}

// lane<32/lane>=32 half exchange: a' = [a_lo|b_lo], b' = [a_hi|b_hi]
__device__ __forceinline__ void plswap(unsigned& a, unsigned& b, int hi) {
#if __has_builtin(__builtin_amdgcn_permlane32_swap)
  typedef __attribute__((ext_vector_type(2))) unsigned uint2_t;
  uint2_t r = __builtin_amdgcn_permlane32_swap(a, b, false, false);
  a = r[0]; b = r[1];
#else
  const unsigned sa = (unsigned)__shfl_xor((int)a, 32);
  const unsigned sb = (unsigned)__shfl_xor((int)b, 32);
  const unsigned an = hi ? sb : a;
  const unsigned bn = hi ? b : sa;
  a = an; b = bn;
#endif
}

// ---------------- fused pre-pass (R13): one block per (bh,kt) ----------
// K -> Kt2[bh][kt][ch(8)][lr(64)][8]: out[ch*512+lr*8+j] = K[d=ch*8+j][k=lr]
// V -> Vt3[bh][kt][kc(8)][d(64)][8]:  out[(kc*64+d)*8+j] = V[d][k=kc*8+j]
#define PST 68
__global__ __launch_bounds__(256, 8)
void eia_prep_kernel(const float* __restrict__ kg, const float* __restrict__ vg,
                     unsigned short* __restrict__ Kt2, unsigned short* __restrict__ Vt2) {
  __shared__ __align__(16) short T[64 * PST];
  const int bh = blockIdx.x >> 5;
  const int kt = blockIdx.x & 31;
  const int t  = threadIdx.x;

  // ---- K phase: float4 loads along k, scatter bf16 to T[k][d] ----
  {
    const int dr = t >> 4;          // 0..15
    const int kq = (t & 15) * 4;    // 0,4,..,60
#pragma unroll
    for (int i = 0; i < 4; ++i) {
      const int d = i * 16 + dr;
      const float4_t f = *(const float4_t*)
          &kg[((size_t)bh * 64 + d) * SEQ + (size_t)(kt * 64 + kq)];
      T[(kq + 0) * PST + d] = f2bf1(f[0]);
      T[(kq + 1) * PST + d] = f2bf1(f[1]);
      T[(kq + 2) * PST + d] = f2bf1(f[2]);
      T[(kq + 3) * PST + d] = f2bf1(f[3]);
    }
  }
  __syncthreads();
  // K writeout (byte-identical to proven layout)
  {
    unsigned short* outt = Kt2 + (size_t)(bh * 32 + kt) * 4096;
#pragma unroll
    for (int rep = 0; rep < 2; ++rep) {
      const int id2 = rep * 256 + t;
      const int lr = id2 & 63, ch = id2 >> 6;
      union { short8_t v; short4_t h[2]; } o;
      o.h[0] = *(const short4_t*)&T[lr * PST + ch * 8];
      o.h[1] = *(const short4_t*)&T[lr * PST + ch * 8 + 4];
      *(short8_t*)&outt[ch * 512 + lr * 8] = o.v;
    }
  }
  __syncthreads();  // K reads of T done before V overwrites

  // ---- V phase: float4 loads along k into T[d][k] (proven pattern) ----
#pragma unroll
  for (int rep = 0; rep < 4; ++rep) {
    const int id2 = rep * 256 + t;
    const int d = id2 >> 4, l4 = (id2 & 15) * 4;
    const float4_t f = *(const float4_t*)
        &vg[((size_t)bh * 64 + d) * SEQ + (size_t)(kt * 64 + l4)];
    union { short4_t s; unsigned u[2]; } p;
    p.u[0] = f2bf2u(f[0], f[1]);
    p.u[1] = f2bf2u(f[2], f[3]);
    *(short4_t*)&T[d * PST + l4] = p.s;
  }
  __syncthreads();
  // Vt3 writeout (byte-identical to R12)
  {
    unsigned short* outt = Vt2 + (size_t)(bh * 32 + kt) * 4096;
#pragma unroll
    for (int rep = 0; rep < 2; ++rep) {
      const int c = rep * 256 + t;
      const int kc = c >> 6, d = c & 63;
      union { short8_t v; short4_t h[2]; } o;
      o.h[0] = *(const short4_t*)&T[d * PST + kc * 8];
      o.h[1] = *(const short4_t*)&T[d * PST + kc * 8 + 4];
      *(short8_t*)&outt[c * 8] = o.v;
    }
  }
}

// ---------------- main fused attention (R12: 32x32 MFMA path, UNCHANGED) ----
// LDS (shorts): K stages [0,4096)|[4096,8192)|[8192,12288)
//               V stages [12288,16384)|[16384,20480)|[20480,24576)
// Q staging overlays [0, 8704) before the first DMA.
__global__ __launch_bounds__(256, 2)
void eia_attn_kernel(const float* __restrict__ qg,
                     const unsigned short* __restrict__ Kt2,
                     const unsigned short* __restrict__ Vt2,
                     const int* __restrict__ klen,
                     float* __restrict__ outg) {
  __shared__ __align__(16) short SM[24576];

  const int tid   = threadIdx.x;
  const int bh    = blockIdx.x & 31;   // XCD = bh%8; 512 blocks = 2/CU
  const int qt    = blockIdx.x >> 5;
  const int q0    = qt * 128;
  const int qw    = tid >> 6;          // wave 0..3: q-tile qw*32
  const int lane  = tid & 63;
  const int l31   = lane & 31;
  const int hi    = lane >> 5;

  const float c = (1.4426950408889634f / (8.0f * 2.9957322735539909f)) *
                  logf((float)klen[bh >> 3]);
  const size_t qb = (size_t)bh * 64 * SEQ;

  // ---- Q stage: fp32 global -> SM[q][d] bf16 (stride 68), c folded ----
#pragma unroll
  for (int rep = 0; rep < 8; ++rep) {
    const int id = rep * 256 + tid;       // 0..2047
    const int d  = id >> 5;               // 0..63
    const int q4 = (id & 31) * 4;
    const float4_t f = *(const float4_t*)&qg[qb + (size_t)d * SEQ + (size_t)(q0 + q4)];
    SM[(q4 + 0) * 68 + d] = f2bf1(c * f[0]);
    SM[(q4 + 1) * 68 + d] = f2bf1(c * f[1]);
    SM[(q4 + 2) * 68 + d] = f2bf1(c * f[2]);
    SM[(q4 + 3) * 68 + d] = f2bf1(c * f[3]);
  }
  __syncthreads();

  // Q B-fragments (32x32x16 B-layout): B[d=s*16+hi*8+j][q=l31], s=0..3
  short8_t qfrag[4];
#pragma unroll
  for (int s = 0; s < 4; ++s) {
    const short* qp = &SM[(qw * 32 + l31) * 68 + s * 16 + hi * 8];
    const short4_t lo = *(const short4_t*)qp;
    const short4_t hh = *(const short4_t*)(qp + 4);
    qfrag[s] = short8_t{lo[0], lo[1], lo[2], lo[3], hh[0], hh[1], hh[2], hh[3]};
  }
  __syncthreads();  // Q reads done before DMA overwrites SM

  // ---- DMA setup: tile = 8 x 1KB instrs; wave qw covers instrs 2qw, 2qw+1 ----
  const char* ksrc = (const char*)Kt2 + (size_t)bh * NKT * 8192 + (2 * qw) * 1024 + lane * 16;
  const char* vsrc = (const char*)Vt2 + (size_t)bh * NKT * 8192 + (2 * qw) * 1024 + lane * 16;
  short* const kdst = &SM[(2 * qw) * 512];            // + stage*4096 (HW adds lane*16B)
  short* const vdst = &SM[12288 + (2 * qw) * 512];

  // per-lane invariant fragment offset (shorts): hi*512 + l31*8
  const int lofs = hi * 512 + l31 * 8;

  const float16_t z16 = {0.f,0.f,0.f,0.f,0.f,0.f,0.f,0.f,
                         0.f,0.f,0.f,0.f,0.f,0.f,0.f,0.f};
  float16_t oacc0 = z16, oacc1 = z16;   // dt = 0,1
  float ls = 0.f;

  // ---- prologue: DMA tiles 0,1 -> stages 0,1 (4 loads/wave/tile) ----
  gld16(ksrc, kdst);               gld16(ksrc + 1024, kdst + 512);
  gld16(vsrc, vdst);               gld16(vsrc + 1024, vdst + 512);
  gld16(ksrc + 8192, kdst + 4096); gld16(ksrc + 8192 + 1024, kdst + 4096 + 512);
  gld16(vsrc + 8192, vdst + 4096); gld16(vsrc + 8192 + 1024, vdst + 4096 + 512);
  // One-time full drain: no issue-order assumption on prologue loads (R9-proven).
  asm volatile("s_waitcnt vmcnt(0)" ::: "memory");

  int  sc = 0;              // stage (shorts offset/4096) of current tile
  int  sn = 2;              // stage of tile kt+2
  size_t gsrc = 2 * 8192;   // byte offset of tile kt+2

  for (int kt = 0; kt < NKT; ++kt) {
    // wait: current tile's 4 loads done; NEXT tile's 4 stay in flight.
    if (kt < NKT - 1) asm volatile("s_waitcnt vmcnt(4)" ::: "memory");
    else              asm volatile("s_waitcnt vmcnt(0)" ::: "memory");
    asm volatile("s_barrier" ::: "memory");

    // issue DMA for tile kt+2 into stage sn (2 compute sections to land)
    if (kt < NKT - 2) {
      const int so = sn * 4096;
      gld16(ksrc + gsrc, kdst + so); gld16(ksrc + gsrc + 1024, kdst + so + 512);
      gld16(vsrc + gsrc, vdst + so); gld16(vsrc + gsrc + 1024, vdst + so + 512);
      gsrc += 8192;
      sn = (sn == 2) ? 0 : sn + 1;
    }
    const int koff = sc * 4096;
    sc = (sc == 2) ? 0 : sc + 1;
    const short* const kb_ = &SM[koff + lofs];           // + kb*256 + s*1024
    const short* const vb_ = &SM[12288 + koff + lofs];   // + dt*256 + ks*1024

    // ---- S^T = K^T * Q : 2 kb-tiles x 4 chained mfma_32x32x16 ----
    float16_t s0 = z16, s1 = z16;
#pragma unroll
    for (int s = 0; s < 4; ++s)
      s0 = mfma3232(*(const short8_t*)(kb_ + s * 1024), qfrag[s], s0);
#pragma unroll
    for (int s = 0; s < 4; ++s)
      s1 = mfma3232(*(const short8_t*)(kb_ + 256 + s * 1024), qfrag[s], s1);

    // ---- exp + lsum + P repack (C->B via cvt_pk + permlane32_swap) ----
    union pfu { short8_t s8; unsigned u[4]; };
    pfu pf[4];
#pragma unroll
    for (int kb = 0; kb < 2; ++kb) {
      float e[16];
#pragma unroll
      for (int r = 0; r < 16; ++r)
        e[r] = fast_exp2(kb == 0 ? s0[r] : s1[r]);
      ls += (((e[0] + e[1]) + (e[2] + e[3])) + ((e[4] + e[5]) + (e[6] + e[7]))) +
            (((e[8] + e[9]) + (e[10] + e[11])) + ((e[12] + e[13]) + (e[14] + e[15])));
#pragma unroll
      for (int ksl = 0; ksl < 2; ++ksl) {
        const int b = ksl * 8;
        unsigned a02 = f2bf2u(e[b + 0], e[b + 1]);
        unsigned b02 = f2bf2u(e[b + 4], e[b + 5]);
        unsigned a13 = f2bf2u(e[b + 2], e[b + 3]);
        unsigned b13 = f2bf2u(e[b + 6], e[b + 7]);
        plswap(a02, b02, hi);   // a02 -> reg t0, b02 -> reg t2
        plswap(a13, b13, hi);   // a13 -> reg t1, b13 -> reg t3
        pf[kb * 2 + ksl].u[0] = a02;
        pf[kb * 2 + ksl].u[1] = a13;
        pf[kb * 2 + ksl].u[2] = b02;
        pf[kb * 2 + ksl].u[3] = b13;
      }
    }

    // ---- O^T += V * P^T : 2 dt-tiles x 4 chained mfma_32x32x16 ----
#pragma unroll
    for (int ks = 0; ks < 4; ++ks)
      oacc0 = mfma3232(*(const short8_t*)(vb_ + ks * 1024), pf[ks].s8, oacc0);
#pragma unroll
    for (int ks = 0; ks < 4; ++ks)
      oacc1 = mfma3232(*(const short8_t*)(vb_ + 256 + ks * 1024), pf[ks].s8, oacc1);
  }

  // ---- epilogue: lsum cross-half add, normalize (lane's q = l31), store ----
  const float lst = ls + __shfl_xor(ls, 32);
  const float inv = 1.0f / lst;
  const size_t ob = qb + (size_t)(q0 + qw * 32 + l31);
#pragma unroll
  for (int r = 0; r < 16; ++r) {
    const int drow = (r & 3) + 8 * (r >> 2) + 4 * hi;
    outg[ob + (size_t)(drow) * SEQ]      = oacc0[r] * inv;
    outg[ob + (size_t)(drow + 32) * SEQ] = oacc1[r] * inv;
  }
}

// ---------------- fallback (ws too small): R2-style, known-good ----------------
#define DPAD  72
#define PPAD  68
__global__ __launch_bounds__(256, 5)
void eia_attn_fb(const float* __restrict__ qg, const float* __restrict__ kg,
                 const float* __restrict__ vg, const int* __restrict__ klen,
                 float* __restrict__ outg) {
  __shared__ __align__(16) short QPs[64 * DPAD];
  __shared__ __align__(16) short Ksf[64 * DPAD];
  __shared__ __align__(16) short Vsf[64 * DPAD];

  const int tid  = threadIdx.x;
  const int bh   = blockIdx.x & 31;
  const int qt   = blockIdx.x >> 5;
  const int q0   = qt * 64;
  const int w    = tid >> 6;
  const int lane = tid & 63;
  const int quad = lane >> 4;
  const int l16  = lane & 15;

  const size_t base = (size_t)bh * 64 * SEQ;
  const float c = (1.4426950408889634f / (8.0f * 2.9957322735539909f)) *
                  logf((float)klen[bh >> 3]);

#pragma unroll
  for (int it = 0; it < 2; ++it) {
    const int e = it * 4 + w;
    float f[8];
#pragma unroll
    for (int j = 0; j < 8; ++j)
      f[j] = c * qg[base + (size_t)(e * 8 + j) * SEQ + (size_t)(q0 + lane)];
    union { short8_t s8; unsigned u[4]; } t;
#pragma unroll
    for (int j = 0; j < 4; ++j) t.u[j] = f2bf2u(f[2 * j], f[2 * j + 1]);
    *(short8_t*)&QPs[lane * DPAD + e * 8] = t.s8;
  }
  __syncthreads();

  short8_t qfrag[2];
#pragma unroll
  for (int s = 0; s < 2; ++s)
    qfrag[s] = *(const short8_t*)&QPs[(w * 16 + l16) * DPAD + s * 32 + quad * 8];

  float4_t oacc[4];
#pragma unroll
  for (int t = 0; t < 4; ++t) { oacc[t][0] = 0.f; oacc[t][1] = 0.f; oacc[t][2] = 0.f; oacc[t][3] = 0.f; }
  float lsumv[4] = {0.f, 0.f, 0.f, 0.f};
  const int pbase = w * (16 * DPAD);

  for (int kt = 0; kt < NKT; ++kt) {
    const int k0 = kt * 64;
#pragma unroll
    for (int it = 0; it < 2; ++it) {
      float f[8];
#pragma unroll
      for (int j = 0; j < 8; ++j)
        f[j] = kg[base + (size_t)((it * 4 + w) * 8 + j) * SEQ + (size_t)(k0 + lane)];
      union { short8_t s8; unsigned u[4]; } t;
#pragma unroll
      for (int j = 0; j < 4; ++j) t.u[j] = f2bf2u(f[2 * j], f[2 * j + 1]);
      *(short8_t*)&Ksf[lane * DPAD + (it * 4 + w) * 8] = t.s8;
    }
#pragma unroll
    for (int it = 0; it < 4; ++it) {
      const int d = it * 16 + (w << 2) + (lane >> 4);
      const float4_t vv = *(const float4_t*)&vg[base + (size_t)d * SEQ + (size_t)(k0 + ((lane & 15) << 2))];
      union { short4_t s4; unsigned u[2]; } t;
      t.u[0] = f2bf2u(vv[0], vv[1]);
      t.u[1] = f2bf2u(vv[2], vv[3]);
      *(short4_t*)&Vsf[d * DPAD + ((lane & 15) << 2)] = t.s4;
    }
    __syncthreads();

    float4_t sacc[4];
#pragma unroll
    for (int t = 0; t < 4; ++t) { sacc[t][0] = 0.f; sacc[t][1] = 0.f; sacc[t][2] = 0.f; sacc[t][3] = 0.f; }
#pragma unroll
    for (int t = 0; t < 4; ++t)
#pragma unroll
      for (int s = 0; s < 2; ++s) {
        const short8_t bf = *(const short8_t*)&Ksf[(t * 16 + l16) * DPAD + s * 32 + quad * 8];
        sacc[t] = mfma32(qfrag[s], bf, sacc[t]);
      }

#pragma unroll
    for (int r = 0; r < 4; ++r) {
      const float p0 = fast_exp2(sacc[0][r]);
      const float p1 = fast_exp2(sacc[1][r]);
      const float p2 = fast_exp2(sacc[2][r]);
      const float p3 = fast_exp2(sacc[3][r]);
      lsumv[r] += (p0 + p1) + (p2 + p3);
      const int prow = pbase + (quad * 4 + r) * PPAD + l16;
      QPs[prow +  0] = f2bf1(p0);
      QPs[prow + 16] = f2bf1(p1);
      QPs[prow + 32] = f2bf1(p2);
      QPs[prow + 48] = f2bf1(p3);
    }

#pragma unroll
    for (int s = 0; s < 2; ++s) {
      const short* pr = &QPs[pbase + l16 * PPAD + s * 32 + quad * 8];
      const short4_t plo = *(const short4_t*)pr;
      const short4_t phi = *(const short4_t*)(pr + 4);
      const short8_t pfv = {plo[0], plo[1], plo[2], plo[3], phi[0], phi[1], phi[2], phi[3]};
#pragma unroll
      for (int t = 0; t < 4; ++t) {
        const short8_t vf = *(const short8_t*)&Vsf[(t * 16 + l16) * DPAD + s * 32 + quad * 8];
        oacc[t] = mfma32(pfv, vf, oacc[t]);
      }
    }
    __syncthreads();
  }

  float inv[4];
#pragma unroll
  for (int r = 0; r < 4; ++r) {
    float v = lsumv[r];
    v += __shfl_xor(v, 1);
    v += __shfl_xor(v, 2);
    v += __shfl_xor(v, 4);
    v += __shfl_xor(v, 8);
    inv[r] = 1.0f / v;
  }
#pragma unroll
  for (int t = 0; t < 4; ++t)
#pragma unroll
    for (int r = 0; r < 4; ++r)
      outg[base + (size_t)(t * 16 + l16) * SEQ +
           (size_t)(q0 + w * 16 + quad * 4 + r)] = oacc[t][r] * inv[r];
}

extern "C" void kernel_launch(void* const* d_in, const int* in_sizes, int n_in,
                              void* d_out, int out_size, void* d_ws, size_t ws_size,
                              hipStream_t stream) {
  const float* q  = (const float*)d_in[0];
  const float* k  = (const float*)d_in[1];
  const float* v  = (const float*)d_in[2];
  const int*   kl = (const int*)d_in[3];
  float* out = (float*)d_out;

  const size_t TEN  = (size_t)NBH * SEQ * 64;
  const size_t need = 2 * TEN * sizeof(unsigned short);  // 16.8 MB

  if (ws_size >= need) {
    unsigned short* Kt2 = (unsigned short*)d_ws;
    unsigned short* Vt2 = Kt2 + TEN;
    eia_prep_kernel<<<1024, 256, 0, stream>>>(k, v, Kt2, Vt2);
    eia_attn_kernel<<<512, 256, 0, stream>>>(q, Kt2, Vt2, kl, out);
  } else {
    eia_attn_fb<<<1024, 256, 0, stream>>>(q, k, v, kl, out);
  }
}